// Round 8
// baseline (1178.929 us; speedup 1.0000x reference)
//
#include <hip/hip_runtime.h>
#include <hip/hip_cooperative_groups.h>

namespace cg = cooperative_groups;

// Problem constants (match reference)
constexpr int kNodes  = 500000;
constexpr int kEdges  = 600000;
constexpr int kGraphs = 1024;
constexpr int kD      = 128;   // feature dim
constexpr int kNP     = 16;    // bin privatization (cuts same-address atomic hits 16x)
constexpr int kBins   = kGraphs * kNP;  // 16384
constexpr int kChunk  = 588;   // per-block edge chunk, 4-aligned; 1024*588 >= 600000

// ---------------------------------------------------------------------------
// Workspace layout (bytes). Total ~3.5 MB (5.86 MB proven safe in r3).
// accN/accE eliminated: graph g == block g, so per-graph sums stay in
// registers across grid.sync() phases.
// ---------------------------------------------------------------------------
constexpr size_t kOrderOff = 0;                       // 600000 i32 (graph-grouped edge ids)
constexpr size_t kCntOff   = 2400000;                 // 16384 i32 bins [g][p]
constexpr size_t kOffsOff  = kCntOff + kBins * 4;     // 16384 i32 segment starts
constexpr size_t kCursOff  = kOffsOff + kBins * 4;    // 16384 i32 scatter cursors

// ---------------------------------------------------------------------------
// One cooperative kernel, 1024 blocks x 256 threads (4 blocks/CU guaranteed
// by __launch_bounds__(256,4): VGPR<=128, LDS ~11KB). Phases separated by
// grid.sync(); every block takes every sync (no early returns -> no hang).
//
//  P0: zero 16384 hist bins; binary-search node range for graph blk
//  P1: edge histogram (privatized by blk&15)  +  node sum (4x-ILP float4)
//  P2: 16384-bin exclusive scan (block 0; others idle ~8us)
//  P3: scatter edge ids into graph-grouped order[] (privatized cursors)
//  P4: edge sum: gather 512B rows via LDS-staged order tiles, 4x-ILP
//  P5: out[g] = relu([nodeSum|edgeSum|u] @ W^T + b)  -- sums from registers
// ---------------------------------------------------------------------------
__global__ __launch_bounds__(256, 4) void mega_kernel(
    const float* __restrict__ x, const int* __restrict__ ei0,
    const float* __restrict__ edge_attr, const float* __restrict__ u,
    const int* __restrict__ batch, const float* __restrict__ W,
    const float* __restrict__ bias, float* __restrict__ out,
    int* __restrict__ order, int* __restrict__ counts,
    int* __restrict__ offs, int* __restrict__ curs) {
  cg::grid_group grid = cg::this_grid();
  const int tid  = threadIdx.x;
  const int blk  = blockIdx.x;
  const int sub  = tid & 31;   // float4 column 0..31
  const int rlane = tid >> 5;  // row lane 0..7

  __shared__ int   s_b[2];
  __shared__ int   s_idx[1024];
  __shared__ float s_red[8][128];
  __shared__ int   s_scan[256];
  __shared__ float s_in[384];

  // ---- P0: zero hist bins + node-range binary search (independent work) ----
  if (tid < kNP) counts[blk * kNP + tid] = 0;
  if (tid < 2) {
    const int target = blk + tid;
    int lo = 0, hi = kNodes;
    while (lo < hi) {
      const int mid = (lo + hi) >> 1;
      if (batch[mid] < target) lo = mid + 1; else hi = mid;
    }
    s_b[tid] = lo;
  }
  __syncthreads();
  const int nStart = s_b[0], nEnd = s_b[1];
  grid.sync();

  // ---- P1a: histogram. kEdges%4==0 and chunks 4-aligned -> pure int4 ----
  {
    const int r = blk * kChunk + tid * 4;
    if (tid * 4 < kChunk && r + 3 < kEdges) {
      const int4 e4 = *reinterpret_cast<const int4*>(ei0 + r);
      int* cp = counts + (blk & (kNP - 1));
      atomicAdd(cp + batch[e4.x] * kNP, 1);
      atomicAdd(cp + batch[e4.y] * kNP, 1);
      atomicAdd(cp + batch[e4.z] * kNP, 1);
      atomicAdd(cp + batch[e4.w] * kNP, 1);
    }
  }

  // ---- P1b: node sum for graph blk (contiguous rows, 4 loads in flight) ----
  float nodeSum;
  {
    float4 a0 = make_float4(0.f, 0.f, 0.f, 0.f);
    float4 a1 = a0, a2 = a0, a3 = a0;
    const float4* rows = reinterpret_cast<const float4*>(x);
    int r = nStart + rlane;
    for (; r + 24 < nEnd; r += 32) {
      const float4 v0 = rows[(size_t)r * 32 + sub];
      const float4 v1 = rows[(size_t)(r + 8) * 32 + sub];
      const float4 v2 = rows[(size_t)(r + 16) * 32 + sub];
      const float4 v3 = rows[(size_t)(r + 24) * 32 + sub];
      a0.x += v0.x; a0.y += v0.y; a0.z += v0.z; a0.w += v0.w;
      a1.x += v1.x; a1.y += v1.y; a1.z += v1.z; a1.w += v1.w;
      a2.x += v2.x; a2.y += v2.y; a2.z += v2.z; a2.w += v2.w;
      a3.x += v3.x; a3.y += v3.y; a3.z += v3.z; a3.w += v3.w;
    }
    for (; r < nEnd; r += 8) {
      const float4 v = rows[(size_t)r * 32 + sub];
      a0.x += v.x; a0.y += v.y; a0.z += v.z; a0.w += v.w;
    }
    a0.x += a1.x + a2.x + a3.x;
    a0.y += a1.y + a2.y + a3.y;
    a0.z += a1.z + a2.z + a3.z;
    a0.w += a1.w + a2.w + a3.w;
    s_red[rlane][sub * 4 + 0] = a0.x;
    s_red[rlane][sub * 4 + 1] = a0.y;
    s_red[rlane][sub * 4 + 2] = a0.z;
    s_red[rlane][sub * 4 + 3] = a0.w;
    __syncthreads();
    float sm = 0.f;
    if (tid < kD) {
#pragma unroll
      for (int k = 0; k < 8; ++k) sm += s_red[k][tid];
    }
    nodeSum = sm;  // graph blk's node_agg[tid], lives in a register to P5
  }
  grid.sync();

  // ---- P2: exclusive scan of 16384 bins (block 0; 64 bins/thread) ----
  if (blk == 0) {
    const int b0 = tid * 64;
    int tot = 0;
    for (int k = 0; k < 64; ++k) tot += counts[b0 + k];
    s_scan[tid] = tot;
    __syncthreads();
    for (int off = 1; off < 256; off <<= 1) {
      const int add = (tid >= off) ? s_scan[tid - off] : 0;
      __syncthreads();
      s_scan[tid] += add;
      __syncthreads();
    }
    int run = s_scan[tid] - tot;  // exclusive base of this thread's bins
    for (int k = 0; k < 64; ++k) {
      const int c = counts[b0 + k];
      offs[b0 + k] = run;
      curs[b0 + k] = run;
      run += c;
    }
  }
  grid.sync();

  // ---- P3: scatter edge ids into graph-grouped order[] ----
  {
    const int r = blk * kChunk + tid * 4;
    if (tid * 4 < kChunk && r + 3 < kEdges) {
      const int4 e4 = *reinterpret_cast<const int4*>(ei0 + r);
      int* cp = curs + (blk & (kNP - 1));
      const int p0 = atomicAdd(cp + batch[e4.x] * kNP, 1);
      const int p1 = atomicAdd(cp + batch[e4.y] * kNP, 1);
      const int p2 = atomicAdd(cp + batch[e4.z] * kNP, 1);
      const int p3 = atomicAdd(cp + batch[e4.w] * kNP, 1);
      order[p0] = r;
      order[p1] = r + 1;
      order[p2] = r + 2;
      order[p3] = r + 3;
    }
  }
  grid.sync();

  // ---- P4: edge sum for graph blk (LDS-staged index tiles, 4x ILP) ----
  float edgeSum;
  {
    const int s = offs[blk * kNP];
    const int e = (blk == kGraphs - 1) ? kEdges : offs[(blk + 1) * kNP];
    float4 a0 = make_float4(0.f, 0.f, 0.f, 0.f);
    float4 a1 = a0, a2 = a0, a3 = a0;
    const float4* rows = reinterpret_cast<const float4*>(edge_attr);
    for (int t0 = s; t0 < e; t0 += 1024) {
      const int n = min(1024, e - t0);
      __syncthreads();  // protect s_idx from previous tile's readers
      for (int i = tid; i < n; i += 256) s_idx[i] = order[t0 + i];
      __syncthreads();
      int i = rlane;
      for (; i + 24 < n; i += 32) {
        const int i0 = s_idx[i],      i1 = s_idx[i + 8];
        const int i2 = s_idx[i + 16], i3 = s_idx[i + 24];
        const float4 v0 = rows[(size_t)i0 * 32 + sub];
        const float4 v1 = rows[(size_t)i1 * 32 + sub];
        const float4 v2 = rows[(size_t)i2 * 32 + sub];
        const float4 v3 = rows[(size_t)i3 * 32 + sub];
        a0.x += v0.x; a0.y += v0.y; a0.z += v0.z; a0.w += v0.w;
        a1.x += v1.x; a1.y += v1.y; a1.z += v1.z; a1.w += v1.w;
        a2.x += v2.x; a2.y += v2.y; a2.z += v2.z; a2.w += v2.w;
        a3.x += v3.x; a3.y += v3.y; a3.z += v3.z; a3.w += v3.w;
      }
      for (; i < n; i += 8) {
        const float4 v = rows[(size_t)s_idx[i] * 32 + sub];
        a0.x += v.x; a0.y += v.y; a0.z += v.z; a0.w += v.w;
      }
    }
    a0.x += a1.x + a2.x + a3.x;
    a0.y += a1.y + a2.y + a3.y;
    a0.z += a1.z + a2.z + a3.z;
    a0.w += a1.w + a2.w + a3.w;
    __syncthreads();  // s_red reuse: P1 readers are long done, but be explicit
    s_red[rlane][sub * 4 + 0] = a0.x;
    s_red[rlane][sub * 4 + 1] = a0.y;
    s_red[rlane][sub * 4 + 2] = a0.z;
    s_red[rlane][sub * 4 + 3] = a0.w;
    __syncthreads();
    float sm = 0.f;
    if (tid < kD) {
#pragma unroll
      for (int k = 0; k < 8; ++k) sm += s_red[k][tid];
    }
    edgeSum = sm;  // graph blk's edge_agg[tid]
  }
  grid.sync();

  // ---- P5: out[blk][tid] = relu(b + [nodeSum|edgeSum|u] . W[tid]) ----
  if (tid < kD) {
    s_in[tid]          = nodeSum;
    s_in[kD + tid]     = edgeSum;
    s_in[2 * kD + tid] = u[(size_t)blk * kD + tid];
  }
  __syncthreads();
  if (tid < kD) {
    float sum = bias[tid];
    const float4* Wr = reinterpret_cast<const float4*>(W + (size_t)tid * 384);
    const float4* Sr = reinterpret_cast<const float4*>(s_in);
#pragma unroll 8
    for (int k = 0; k < 96; ++k) {
      const float4 w = Wr[k];
      const float4 s = Sr[k];
      sum = fmaf(w.x, s.x, sum);
      sum = fmaf(w.y, s.y, sum);
      sum = fmaf(w.z, s.z, sum);
      sum = fmaf(w.w, s.w, sum);
    }
    out[(size_t)blk * kD + tid] = fmaxf(sum, 0.f);
  }
}

// ---------------------------------------------------------------------------
extern "C" void kernel_launch(void* const* d_in, const int* in_sizes, int n_in,
                              void* d_out, int out_size, void* d_ws,
                              size_t ws_size, hipStream_t stream) {
  const float* x         = (const float*)d_in[0];
  const int*   ei0       = (const int*)d_in[1];   // row 0 of [2][kEdges]
  const float* edge_attr = (const float*)d_in[2];
  const float* u         = (const float*)d_in[3];
  const int*   batch     = (const int*)d_in[4];
  const float* W         = (const float*)d_in[5];
  const float* bias      = (const float*)d_in[6];
  float*       out       = (float*)d_out;

  char* ws = (char*)d_ws;
  int* order  = (int*)(ws + kOrderOff);
  int* counts = (int*)(ws + kCntOff);
  int* offs   = (int*)(ws + kOffsOff);
  int* curs   = (int*)(ws + kCursOff);

  void* args[] = {(void*)&x,     (void*)&ei0,  (void*)&edge_attr,
                  (void*)&u,     (void*)&batch, (void*)&W,
                  (void*)&bias,  (void*)&out,   (void*)&order,
                  (void*)&counts, (void*)&offs, (void*)&curs};
  hipLaunchCooperativeKernel((void*)mega_kernel, dim3(kGraphs), dim3(256),
                             args, 0, stream);
}